// Round 2
// baseline (187.368 us; speedup 1.0000x reference)
//
#include <hip/hip_runtime.h>
#include <hip/hip_bf16.h>

// ---------------------------------------------------------------------------
// EdgeConvNet fused kernel — Round 2: pure-VALU fp32 (correct dtypes).
//
// Device dtypes (per harness contract + round-1 NaN evidence):
//   all float tensors fp32, edge_index int32 (converted from int64), out fp32.
//
// Mapping: 2 threads per edge (parity p owns conv channels o = 4p..4p+3).
//  - acc[4][16] fp32 accumulators for fc1 (static indexing only -> VGPRs)
//  - w1^T staged as fp32 [64][16] in LDS; per-f column read as 4x float4
//    with a wave-uniform address (pure broadcast, no bank conflicts)
//  - features gathered as 16B float4 loads (4 fp32), next chunk prefetched
//  - fc2/fc3/sigmoid fused in epilogue; halves combined via __shfl_xor(z,1)
// ---------------------------------------------------------------------------

#define FMA16(O, T) do { \
    acc[O][ 0]=fmaf((T),wv0.x,acc[O][ 0]); acc[O][ 1]=fmaf((T),wv0.y,acc[O][ 1]); \
    acc[O][ 2]=fmaf((T),wv0.z,acc[O][ 2]); acc[O][ 3]=fmaf((T),wv0.w,acc[O][ 3]); \
    acc[O][ 4]=fmaf((T),wv1.x,acc[O][ 4]); acc[O][ 5]=fmaf((T),wv1.y,acc[O][ 5]); \
    acc[O][ 6]=fmaf((T),wv1.z,acc[O][ 6]); acc[O][ 7]=fmaf((T),wv1.w,acc[O][ 7]); \
    acc[O][ 8]=fmaf((T),wv2.x,acc[O][ 8]); acc[O][ 9]=fmaf((T),wv2.y,acc[O][ 9]); \
    acc[O][10]=fmaf((T),wv2.z,acc[O][10]); acc[O][11]=fmaf((T),wv2.w,acc[O][11]); \
    acc[O][12]=fmaf((T),wv3.x,acc[O][12]); acc[O][13]=fmaf((T),wv3.y,acc[O][13]); \
    acc[O][14]=fmaf((T),wv3.z,acc[O][14]); acc[O][15]=fmaf((T),wv3.w,acc[O][15]); \
} while (0)

#define DO_F(F, X1, X2) do { \
    const float x1_ = (X1), x2_ = (X2); \
    const float t0_ = fmaxf(fmaf(a0, x1_, fmaf(c0, x2_, q0)), 0.f); \
    const float t1_ = fmaxf(fmaf(a1, x1_, fmaf(c1, x2_, q1)), 0.f); \
    const float t2_ = fmaxf(fmaf(a2, x1_, fmaf(c2, x2_, q2)), 0.f); \
    const float t3_ = fmaxf(fmaf(a3, x1_, fmaf(c3, x2_, q3)), 0.f); \
    const float4* wc_ = reinterpret_cast<const float4*>(&sW1T[(F)][0]); \
    const float4 wv0 = wc_[0], wv1 = wc_[1], wv2 = wc_[2], wv3 = wc_[3]; \
    FMA16(0, t0_); FMA16(1, t1_); FMA16(2, t2_); FMA16(3, t3_); \
} while (0)

__global__ __launch_bounds__(256) void edgeconv_fused(
    const float* __restrict__ features,   // (50000, 64) fp32
    const int*   __restrict__ edge_index, // (2, E) int32
    const float* __restrict__ conv_w,     // (8, 2)
    const float* __restrict__ conv_b,     // (8)
    const float* __restrict__ w1,         // (16, 64)
    const float* __restrict__ b1,         // (16)
    const float* __restrict__ w2,         // (16)
    const float* __restrict__ b2,         // (1)
    const float* __restrict__ w3,         // (8)
    const float* __restrict__ b3,         // (1)
    float*       __restrict__ out,        // (E)
    int nEdges)
{
    __shared__ float sW1T[64][16];   // w1 transposed: [f][g]
    __shared__ float sB1[16], sW2[16], sW3[8], sCA[8], sCC[8], sCB[8];
    __shared__ float sB2s[1], sB3s[1];

    const int tid = threadIdx.x;
    #pragma unroll
    for (int it = 0; it < 4; ++it) {
        const int idx = tid + it * 256;           // idx = g*64 + f
        sW1T[idx & 63][idx >> 6] = w1[idx];
    }
    if (tid < 16) {
        sB1[tid] = b1[tid];
        sW2[tid] = w2[tid];
    } else if (tid < 24) {
        const int o = tid - 16;
        sW3[o] = w3[o];
        sCA[o] = conv_w[2 * o];
        sCC[o] = conv_w[2 * o + 1];
        sCB[o] = conv_b[o];
    } else if (tid == 24) {
        sB2s[0] = b2[0];
        sB3s[0] = b3[0];
    }
    __syncthreads();

    const int gt = blockIdx.x * 256 + tid;
    const int e  = gt >> 1;           // edge id
    if (e >= nEdges) return;
    const int p  = tid & 1;           // parity: which 4 conv channels
    const int ob = p << 2;

    const int sN = edge_index[e];
    const int dN = edge_index[nEdges + e];
    const float4* __restrict__ F1 = reinterpret_cast<const float4*>(features + (size_t)sN * 64);
    const float4* __restrict__ F2 = reinterpret_cast<const float4*>(features + (size_t)dN * 64);

    const float a0 = sCA[ob + 0], a1 = sCA[ob + 1], a2 = sCA[ob + 2], a3 = sCA[ob + 3];
    const float c0 = sCC[ob + 0], c1 = sCC[ob + 1], c2 = sCC[ob + 2], c3 = sCC[ob + 3];
    const float q0 = sCB[ob + 0], q1 = sCB[ob + 1], q2 = sCB[ob + 2], q3 = sCB[ob + 3];

    float acc[4][16];
    #pragma unroll
    for (int o = 0; o < 4; ++o)
        #pragma unroll
        for (int g = 0; g < 16; ++g) acc[o][g] = 0.f;

    // main loop: 16 chunks of 4 features; prefetch next chunk's 16B loads
    float4 u1 = F1[0];
    float4 u2 = F2[0];
    #pragma unroll 1
    for (int c = 0; c < 16; ++c) {
        const int cn = (c + 1) & 15;      // branchless prefetch (wraps, cached)
        const float4 n1 = F1[cn];
        const float4 n2 = F2[cn];
        const int fb = c * 4;
        DO_F(fb + 0, u1.x, u2.x);
        DO_F(fb + 1, u1.y, u2.y);
        DO_F(fb + 2, u1.z, u2.z);
        DO_F(fb + 3, u1.w, u2.w);
        u1 = n1; u2 = n2;
    }

    // epilogue: fc1 bias+relu, fc2, fc3 partial, combine halves, sigmoid
    const float b2v = sB2s[0];
    float z = 0.f;
    #pragma unroll
    for (int o = 0; o < 4; ++o) {
        float h2 = b2v;
        #pragma unroll
        for (int g = 0; g < 16; ++g) {
            const float h1 = fmaxf(acc[o][g] + sB1[g], 0.f);
            h2 = fmaf(h1, sW2[g], h2);
        }
        h2 = fmaxf(h2, 0.f);
        z = fmaf(h2, sW3[ob + o], z);
    }
    z += __shfl_xor(z, 1);            // combine the two 4-channel halves
    z += sB3s[0];
    const float sg = 1.0f / (1.0f + __expf(-z));
    if (p == 0) out[e] = sg;
}

extern "C" void kernel_launch(void* const* d_in, const int* in_sizes, int n_in,
                              void* d_out, int out_size, void* d_ws, size_t ws_size,
                              hipStream_t stream) {
    // setup_inputs order:
    // 0:x 1:features 2:edge_index 3:conv_w 4:conv_b 5:w1 6:b1 7:w2 8:b2 9:w3 10:b3
    const float* features = (const float*)d_in[1];
    const int*   edge_idx = (const int*)d_in[2];
    const float* conv_w   = (const float*)d_in[3];
    const float* conv_b   = (const float*)d_in[4];
    const float* w1       = (const float*)d_in[5];
    const float* b1       = (const float*)d_in[6];
    const float* w2       = (const float*)d_in[7];
    const float* b2       = (const float*)d_in[8];
    const float* w3       = (const float*)d_in[9];
    const float* b3       = (const float*)d_in[10];
    float*       out      = (float*)d_out;

    const int nEdges   = in_sizes[2] / 2;        // (2, E)
    const int nThreads = nEdges * 2;             // 2 threads per edge
    const dim3 grid((nThreads + 255) / 256);
    const dim3 block(256);
    edgeconv_fused<<<grid, block, 0, stream>>>(features, edge_idx,
                                               conv_w, conv_b, w1, b1, w2, b2, w3, b3,
                                               out, nEdges);
}

// Round 3
// 125.362 us; speedup vs baseline: 1.4946x; 1.4946x over previous
//
#include <hip/hip_runtime.h>
#include <hip/hip_bf16.h>

// ---------------------------------------------------------------------------
// EdgeConvNet — Round 3: fc1 on MFMA (mfma_f32_16x16x32_bf16).
//
// Tile = 2 edges: C[16][16] = A[16 rows = 2edges x 8ch][K=64 feats] x
//                             B[K=64][16 cols = g], K split into 2 MFMAs.
// A built on the fly: conv(ch, f) = relu(a[ch]*x1[f] + c[ch]*x2[f] + b[ch]),
// packed to bf16. B = w1 (bf16), held in VGPRs for the whole kernel.
// Both fragments use the SAME (lane-group, elem)->f map, so the hardware's
// internal k-permutation cancels (sum over k is permutation-invariant).
// C/D layout (HW-verified): col = lane&15, row = (lane>>4)*4 + reg.
// Epilogue: fc2 = xor{1,2,4,8} butterfly over cols; fc3 = xor(16) across
// row-groups; sigmoid; lanes 0 / 32 store the 2 edges.
// Each wave processes 16 edges (8 tiles); edge indices preloaded once and
// broadcast per-tile via __shfl; next tile's feature gathers prefetched.
// ---------------------------------------------------------------------------

typedef short bf16x8 __attribute__((ext_vector_type(8)));
typedef float f32x4  __attribute__((ext_vector_type(4)));

static __device__ __forceinline__ short f2bf(float f) {
    union { __hip_bfloat16 h; short s; } u;
    u.h = __float2bfloat16(f);
    return u.s;
}

__global__ __launch_bounds__(256) void edgeconv_mfma(
    const float* __restrict__ features,   // (50000, 64) fp32
    const int*   __restrict__ edge_index, // (2, E) int32
    const float* __restrict__ conv_w,     // (8, 2)
    const float* __restrict__ conv_b,     // (8)
    const float* __restrict__ w1,         // (16, 64)
    const float* __restrict__ b1,         // (16)
    const float* __restrict__ w2,         // (16)
    const float* __restrict__ b2,         // (1)
    const float* __restrict__ w3,         // (8)
    const float* __restrict__ b3,         // (1)
    float*       __restrict__ out,        // (E)
    int nEdges)
{
    const int tid = threadIdx.x;
    const int l   = tid & 63;
    const int wid = tid >> 6;
    const int grp = l >> 4;        // 0..3 : k-slice group
    const int col = l & 15;        // A-row / B-col index for fragments
    const int ch  = col & 7;       // conv channel of this A row
    const int el  = col >> 3;      // which edge of the pair (0/1)

    // --- B fragments (w1, persistent in VGPRs). elem i <-> f = kh*32+grp*8+i
    const float* w1r = w1 + col * 64 + grp * 8;
    bf16x8 bf0, bf1;
    #pragma unroll
    for (int i = 0; i < 8; ++i) {
        bf0[i] = f2bf(w1r[i]);
        bf1[i] = f2bf(w1r[32 + i]);
    }

    // --- small params
    const float ca  = conv_w[2 * ch];
    const float cc  = conv_w[2 * ch + 1];
    const float cb  = conv_b[ch];
    const float b1v = b1[col];
    const float w2v = w2[col];
    const float b2v = b2[0];
    const float b3v = b3[0];
    float w3r[4];
    #pragma unroll
    for (int r = 0; r < 4; ++r) w3r[r] = w3[(grp & 1) * 4 + r];

    // --- this wave's 16 edges; indices preloaded into lanes 0..15 pattern
    const int ebase = (blockIdx.x * 4 + wid) * 16;
    const int ce    = min(ebase + col, nEdges - 1);
    const int vsrc  = edge_index[ce];
    const int vdst  = edge_index[nEdges + ce];

    const int fo = grp * 2;        // float4 offset of this lane's k-slice

    // preload tile 0 features (8x float4 per lane; coalescer dedups)
    f32x4 x1[4], x2[4];
    {
        const int sn = __shfl(vsrc, el);
        const int dn = __shfl(vdst, el);
        const f32x4* q1 = (const f32x4*)(features + (size_t)sn * 64);
        const f32x4* q2 = (const f32x4*)(features + (size_t)dn * 64);
        x1[0] = q1[fo]; x1[1] = q1[fo + 1]; x1[2] = q1[fo + 8]; x1[3] = q1[fo + 9];
        x2[0] = q2[fo]; x2[1] = q2[fo + 1]; x2[2] = q2[fo + 8]; x2[3] = q2[fo + 9];
    }

    #pragma unroll
    for (int t = 0; t < 8; ++t) {
        // prefetch next tile's features (compile-time-skipped on last iter)
        f32x4 nx1[4], nx2[4];
        if (t < 7) {
            const int sn = __shfl(vsrc, 2 * (t + 1) + el);
            const int dn = __shfl(vdst, 2 * (t + 1) + el);
            const f32x4* q1 = (const f32x4*)(features + (size_t)sn * 64);
            const f32x4* q2 = (const f32x4*)(features + (size_t)dn * 64);
            nx1[0] = q1[fo]; nx1[1] = q1[fo + 1]; nx1[2] = q1[fo + 8]; nx1[3] = q1[fo + 9];
            nx2[0] = q2[fo]; nx2[1] = q2[fo + 1]; nx2[2] = q2[fo + 8]; nx2[3] = q2[fo + 9];
        }

        // conv + relu + bf16 pack -> A fragments (same elem->f map as B)
        bf16x8 af0, af1;
        #pragma unroll
        for (int i = 0; i < 8; ++i) {
            const float u0 = x1[i >> 2][i & 3];
            const float v0 = x2[i >> 2][i & 3];
            af0[i] = f2bf(fmaxf(fmaf(ca, u0, fmaf(cc, v0, cb)), 0.f));
            const float u1 = x1[2 + (i >> 2)][i & 3];
            const float v1 = x2[2 + (i >> 2)][i & 3];
            af1[i] = f2bf(fmaxf(fmaf(ca, u1, fmaf(cc, v1, cb)), 0.f));
        }

        // fc1 via MFMA, fp32 accum
        f32x4 acc = {0.f, 0.f, 0.f, 0.f};
        acc = __builtin_amdgcn_mfma_f32_16x16x32_bf16(af0, bf0, acc, 0, 0, 0);
        acc = __builtin_amdgcn_mfma_f32_16x16x32_bf16(af1, bf1, acc, 0, 0, 0);

        // epilogue: bias+relu, fc2 (reduce over cols), fc3 (reduce over rows)
        float pr[4];
        #pragma unroll
        for (int r = 0; r < 4; ++r) {
            const float h1 = fmaxf(acc[r] + b1v, 0.f);
            pr[r] = h1 * w2v;
        }
        #pragma unroll
        for (int m = 1; m <= 8; m <<= 1) {
            #pragma unroll
            for (int r = 0; r < 4; ++r) pr[r] += __shfl_xor(pr[r], m);
        }
        float zp = 0.f;
        #pragma unroll
        for (int r = 0; r < 4; ++r) {
            const float h2 = fmaxf(pr[r] + b2v, 0.f);
            zp = fmaf(h2, w3r[r], zp);
        }
        const float z  = zp + __shfl_xor(zp, 16) + b3v;
        const float sg = 1.0f / (1.0f + __expf(-z));
        if ((l & 31) == 0) {
            const int e = ebase + 2 * t + (l >> 5);
            if (e < nEdges) out[e] = sg;
        }

        if (t < 7) {
            #pragma unroll
            for (int i = 0; i < 4; ++i) { x1[i] = nx1[i]; x2[i] = nx2[i]; }
        }
    }
}

extern "C" void kernel_launch(void* const* d_in, const int* in_sizes, int n_in,
                              void* d_out, int out_size, void* d_ws, size_t ws_size,
                              hipStream_t stream) {
    // 0:x 1:features 2:edge_index 3:conv_w 4:conv_b 5:w1 6:b1 7:w2 8:b2 9:w3 10:b3
    const float* features = (const float*)d_in[1];
    const int*   edge_idx = (const int*)d_in[2];
    const float* conv_w   = (const float*)d_in[3];
    const float* conv_b   = (const float*)d_in[4];
    const float* w1       = (const float*)d_in[5];
    const float* b1       = (const float*)d_in[6];
    const float* w2       = (const float*)d_in[7];
    const float* b2       = (const float*)d_in[8];
    const float* w3       = (const float*)d_in[9];
    const float* b3       = (const float*)d_in[10];
    float*       out      = (float*)d_out;

    const int nEdges = in_sizes[2] / 2;          // (2, E)
    // each block: 4 waves x 16 edges = 64 edges
    const dim3 grid((nEdges + 63) / 64);
    const dim3 block(256);
    edgeconv_mfma<<<grid, block, 0, stream>>>(features, edge_idx,
                                              conv_w, conv_b, w1, b1, w2, b2, w3, b3,
                                              out, nEdges);
}